// Round 2
// baseline (216.241 us; speedup 1.0000x reference)
//
#include <hip/hip_runtime.h>

#define NB 64
#define NP 32768
#define NA 14
#define NC 10
#define NANCH (NB * NP)            // 2097152 anchors
#define TILE 256                   // anchors per block
#define MAIN_BLOCKS (NANCH / TILE) // 8192

// ws layout (16 bytes used):
//   ws[0] : double  loss accumulator (loc + pos-ce + mined-neg-ce)
//   ws[1] : u64     num_pos
// zeroed via hipMemsetAsync at the start of every kernel_launch.

__global__ __launch_bounds__(256) void ssd_main(
    const float* __restrict__ p,
    const float* __restrict__ loc_t,
    const int* __restrict__ conf_t,
    double* __restrict__ ws)
{
    // p-tile staged in LDS: 256 anchors x 14 floats = 14336 B
    __shared__ float sp[TILE * NA];

    const int tid = threadIdx.x;
    const size_t abase = (size_t)blockIdx.x * TILE;   // first anchor of tile
    const size_t fbase = abase * NA;                  // float offset into p

    // ---- coalesced stage: 896 float4 chunks, lane-contiguous ----
    const float4* psrc = reinterpret_cast<const float4*>(p + fbase);
    float4* sdst = reinterpret_cast<float4*>(sp);
#pragma unroll
    for (int k = 0; k < 3; ++k)
        sdst[tid + k * 256] = psrc[tid + k * 256];
    if (tid < 128)
        sdst[768 + tid] = psrc[768 + tid];

    // ---- per-anchor direct loads (already lane-contiguous) ----
    float4 lt = reinterpret_cast<const float4*>(loc_t)[abase + tid];
    int t = conf_t[abase + tid];

    __syncthreads();

    // ---- read own anchor row from LDS (8B-aligned float2 reads) ----
    float x[14];
    const float2* row = reinterpret_cast<const float2*>(&sp[tid * NA]);
#pragma unroll
    for (int j = 0; j < 7; ++j) {
        float2 w = row[j];
        x[2 * j]     = w.x;
        x[2 * j + 1] = w.y;
    }

    // stable logsumexp over conf logits x[4..13]
    float m = x[4];
#pragma unroll
    for (int j = 5; j < 14; ++j) m = fmaxf(m, x[j]);
    float s = 0.f;
#pragma unroll
    for (int j = 4; j < 14; ++j) s += __expf(x[j] - m);
    float lse = m + __logf(s);

    // target logit via select chain (no runtime register indexing)
    float tgt = x[4];
#pragma unroll
    for (int j = 1; j < 10; ++j) tgt = (t == j) ? x[4 + j] : tgt;
    float ce = lse - tgt;

    float loss = 0.f;
    int cnt = 0;
    if (t > 0) {
        loss = ce;
        const float* ltf = reinterpret_cast<const float*>(&lt);
#pragma unroll
        for (int j = 0; j < 4; ++j) {
            float d  = x[j] - ltf[j];
            float ad = fabsf(d);
            loss += (ad < 1.f) ? (0.5f * d * d) : (ad - 0.5f);
        }
        cnt = 1;
    }

    // ---- wave64 reduce in double, cross-wave via LDS, 1 atomic/block ----
    double dl = (double)loss;
#pragma unroll
    for (int off = 32; off > 0; off >>= 1) {
        dl  += __shfl_down(dl, off, 64);
        cnt += __shfl_down(cnt, off, 64);
    }
    __shared__ double sL[4];
    __shared__ int    sC[4];
    int lane = tid & 63, wid = tid >> 6;
    if (lane == 0) { sL[wid] = dl; sC[wid] = cnt; }
    __syncthreads();
    if (tid == 0) {
        double tot = sL[0] + sL[1] + sL[2] + sL[3];
        long long c = (long long)sC[0] + sC[1] + sC[2] + sC[3];
        atomicAdd(ws, tot);
        atomicAdd(reinterpret_cast<unsigned long long*>(ws + 1),
                  (unsigned long long)c);
    }
}

// loss_c for anchor i of a row: ce if negative anchor, else 0.
__device__ __forceinline__ float neg_conf_loss(
    const float* __restrict__ prow, const int* __restrict__ crow, int i)
{
    int t = crow[i];
    if (t > 0) return 0.f;
    const float* v = prow + (size_t)i * NA + 4;
    float m = v[0];
#pragma unroll
    for (int j = 1; j < NC; ++j) m = fmaxf(m, v[j]);
    float s = 0.f;
#pragma unroll
    for (int j = 0; j < NC; ++j) s += __expf(v[j] - m);
    return (m + __logf(s)) - v[0];   // t == 0 -> target logit is v[0]
}

// General hard-negative mining: per row, sum of top-num_neg loss_c values
// via 8-bit MSB-first radix select on float bits (loss_c >= 0 -> monotone).
// For the bench inputs num_neg <= 0 and every block exits immediately.
__global__ __launch_bounds__(256) void ssd_mine(
    const float* __restrict__ p,
    const int* __restrict__ conf_t,
    double* __restrict__ ws)
{
    long long np = (long long)*reinterpret_cast<const unsigned long long*>(ws + 1);
    long long nn = 3 * np;
    long long ub = (long long)NP - np;
    if (ub < nn) nn = ub;
    if (nn <= 0) return;                      // <- taken for bench inputs

    const float* prow = p + (size_t)blockIdx.x * NP * NA;
    const int*   crow = conf_t + (size_t)blockIdx.x * NP;

    __shared__ unsigned int hist[256];
    __shared__ unsigned int s_prefix;
    __shared__ long long    s_want;

    unsigned int prefix = 0;
    long long want = nn;                      // 1-indexed rank (largest)

    for (int pass = 0; pass < 4; ++pass) {
        int shift = 24 - 8 * pass;
        hist[threadIdx.x] = 0;
        __syncthreads();
        for (int i = threadIdx.x; i < NP; i += 256) {
            unsigned int k = __float_as_uint(neg_conf_loss(prow, crow, i));
            bool match = (pass == 0) || ((k >> (shift + 8)) == prefix);
            if (match) atomicAdd(&hist[(k >> shift) & 255u], 1u);
        }
        __syncthreads();
        if (threadIdx.x == 0) {
            unsigned long long cum = 0;
            int d = 255;
            for (; d > 0; --d) {              // falls through to d=0
                unsigned long long h = hist[d];
                if (cum + h >= (unsigned long long)want) break;
                cum += h;
            }
            s_want   = want - (long long)cum;
            s_prefix = (prefix << 8) | (unsigned int)d;
        }
        __syncthreads();
        prefix = s_prefix;
        want   = s_want;
        __syncthreads();
    }

    // prefix == float bits of the nn-th largest value T.
    float T = __uint_as_float(prefix);
    double sgt = 0.0;
    long long cgt = 0;
    for (int i = threadIdx.x; i < NP; i += 256) {
        float lc = neg_conf_loss(prow, crow, i);
        if (__float_as_uint(lc) > prefix) { sgt += (double)lc; ++cgt; }
    }
#pragma unroll
    for (int off = 32; off > 0; off >>= 1) {
        sgt += __shfl_down(sgt, off, 64);
        cgt += __shfl_down(cgt, off, 64);
    }
    __shared__ double    rL[4];
    __shared__ long long rC[4];
    int lane = threadIdx.x & 63, wid = threadIdx.x >> 6;
    if (lane == 0) { rL[wid] = sgt; rC[wid] = cgt; }
    __syncthreads();
    if (threadIdx.x == 0) {
        double stot = rL[0] + rL[1] + rL[2] + rL[3];
        long long ctot = rC[0] + rC[1] + rC[2] + rC[3];
        double rowsum = stot + (double)(nn - ctot) * (double)T;
        atomicAdd(ws, rowsum);
    }
}

__global__ void ssd_final(const double* __restrict__ ws,
                          float* __restrict__ out)
{
    double np = (double)*reinterpret_cast<const unsigned long long*>(ws + 1);
    out[0] = (float)(ws[0] / np);
}

extern "C" void kernel_launch(void* const* d_in, const int* in_sizes, int n_in,
                              void* d_out, int out_size, void* d_ws, size_t ws_size,
                              hipStream_t stream)
{
    const float* p      = (const float*)d_in[0];
    const float* loc_t  = (const float*)d_in[1];
    const int*   conf_t = (const int*)d_in[2];
    float*  out = (float*)d_out;
    double* ws  = (double*)d_ws;

    hipMemsetAsync(d_ws, 0, 16, stream);
    ssd_main<<<MAIN_BLOCKS, 256, 0, stream>>>(p, loc_t, conf_t, ws);
    ssd_mine<<<NB, 256, 0, stream>>>(p, conf_t, ws);
    ssd_final<<<1, 1, 0, stream>>>(ws, out);
}

// Round 3
// 42.751 us; speedup vs baseline: 5.0582x; 5.0582x over previous
//
#include <hip/hip_runtime.h>

#define NB 64
#define NP 32768
#define NA 14
#define NC 10
#define NANCH (NB * NP)            // 2097152 anchors
#define TILE 256                   // anchors per block
#define MAIN_BLOCKS (NANCH / TILE) // 8192

// ws layout (doubles):
//   ws[0            .. MAIN_BLOCKS-1]   per-block loss partial
//   ws[MAIN_BLOCKS  .. 2*MAIN_BLOCKS-1] per-block pos-count partial (exact in double)
//   ws[ACC_LOSS] total loss   (written by reduce; mine atomicAdds; final reads)
//   ws[ACC_NPOS] num_pos      (written by reduce)
// Every location is written before it is read each launch -> no memset needed.
#define ACC_LOSS (2 * MAIN_BLOCKS)
#define ACC_NPOS (2 * MAIN_BLOCKS + 1)

__global__ __launch_bounds__(256) void ssd_main(
    const float* __restrict__ p,
    const float* __restrict__ loc_t,
    const int* __restrict__ conf_t,
    double* __restrict__ ws)
{
    // p-tile staged in LDS: 256 anchors x 14 floats = 14336 B
    __shared__ float sp[TILE * NA];

    const int tid = threadIdx.x;
    const size_t abase = (size_t)blockIdx.x * TILE;   // first anchor of tile
    const size_t fbase = abase * NA;                  // float offset into p

    // ---- coalesced stage: 896 float4 chunks, lane-contiguous ----
    const float4* psrc = reinterpret_cast<const float4*>(p + fbase);
    float4* sdst = reinterpret_cast<float4*>(sp);
#pragma unroll
    for (int k = 0; k < 3; ++k)
        sdst[tid + k * 256] = psrc[tid + k * 256];
    if (tid < 128)
        sdst[768 + tid] = psrc[768 + tid];

    // ---- per-anchor direct loads (already lane-contiguous) ----
    float4 lt = reinterpret_cast<const float4*>(loc_t)[abase + tid];
    int t = conf_t[abase + tid];

    __syncthreads();

    // ---- read own anchor row from LDS (8B-aligned float2 reads) ----
    float x[14];
    const float2* row = reinterpret_cast<const float2*>(&sp[tid * NA]);
#pragma unroll
    for (int j = 0; j < 7; ++j) {
        float2 w = row[j];
        x[2 * j]     = w.x;
        x[2 * j + 1] = w.y;
    }

    // stable logsumexp over conf logits x[4..13]
    float m = x[4];
#pragma unroll
    for (int j = 5; j < 14; ++j) m = fmaxf(m, x[j]);
    float s = 0.f;
#pragma unroll
    for (int j = 4; j < 14; ++j) s += __expf(x[j] - m);
    float lse = m + __logf(s);

    // target logit via select chain (no runtime register indexing)
    float tgt = x[4];
#pragma unroll
    for (int j = 1; j < 10; ++j) tgt = (t == j) ? x[4 + j] : tgt;
    float ce = lse - tgt;

    float loss = 0.f;
    int cnt = 0;
    if (t > 0) {
        loss = ce;
        const float* ltf = reinterpret_cast<const float*>(&lt);
#pragma unroll
        for (int j = 0; j < 4; ++j) {
            float d  = x[j] - ltf[j];
            float ad = fabsf(d);
            loss += (ad < 1.f) ? (0.5f * d * d) : (ad - 0.5f);
        }
        cnt = 1;
    }

    // ---- wave64 reduce in double, cross-wave via LDS, 1 STORE per block ----
    double dl = (double)loss;
#pragma unroll
    for (int off = 32; off > 0; off >>= 1) {
        dl  += __shfl_down(dl, off, 64);
        cnt += __shfl_down(cnt, off, 64);
    }
    __shared__ double sL[4];
    __shared__ int    sC[4];
    int lane = tid & 63, wid = tid >> 6;
    if (lane == 0) { sL[wid] = dl; sC[wid] = cnt; }
    __syncthreads();
    if (tid == 0) {
        ws[blockIdx.x] = sL[0] + sL[1] + sL[2] + sL[3];
        ws[MAIN_BLOCKS + blockIdx.x] =
            (double)(sC[0] + sC[1] + sC[2] + sC[3]);
    }
}

// Sum the per-block partials -> ws[ACC_LOSS], ws[ACC_NPOS].
__global__ __launch_bounds__(256) void ssd_reduce(double* __restrict__ ws)
{
    const int tid = threadIdx.x;
    double l = 0.0, c = 0.0;
    for (int i = tid; i < MAIN_BLOCKS; i += 256) {
        l += ws[i];
        c += ws[MAIN_BLOCKS + i];
    }
#pragma unroll
    for (int off = 32; off > 0; off >>= 1) {
        l += __shfl_down(l, off, 64);
        c += __shfl_down(c, off, 64);
    }
    __shared__ double sL[4], sC[4];
    int lane = tid & 63, wid = tid >> 6;
    if (lane == 0) { sL[wid] = l; sC[wid] = c; }
    __syncthreads();
    if (tid == 0) {
        ws[ACC_LOSS] = sL[0] + sL[1] + sL[2] + sL[3];
        ws[ACC_NPOS] = sC[0] + sC[1] + sC[2] + sC[3];
    }
}

// loss_c for anchor i of a row: ce if negative anchor, else 0.
__device__ __forceinline__ float neg_conf_loss(
    const float* __restrict__ prow, const int* __restrict__ crow, int i)
{
    int t = crow[i];
    if (t > 0) return 0.f;
    const float* v = prow + (size_t)i * NA + 4;
    float m = v[0];
#pragma unroll
    for (int j = 1; j < NC; ++j) m = fmaxf(m, v[j]);
    float s = 0.f;
#pragma unroll
    for (int j = 0; j < NC; ++j) s += __expf(v[j] - m);
    return (m + __logf(s)) - v[0];   // t == 0 -> target logit is v[0]
}

// General hard-negative mining: per row, sum of top-num_neg loss_c values
// via 8-bit MSB-first radix select on float bits (loss_c >= 0 -> monotone).
// For the bench inputs num_neg <= 0 and every block exits immediately.
__global__ __launch_bounds__(256) void ssd_mine(
    const float* __restrict__ p,
    const int* __restrict__ conf_t,
    double* __restrict__ ws)
{
    long long np = (long long)ws[ACC_NPOS];
    long long nn = 3 * np;
    long long ub = (long long)NP - np;
    if (ub < nn) nn = ub;
    if (nn <= 0) return;                      // <- taken for bench inputs

    const float* prow = p + (size_t)blockIdx.x * NP * NA;
    const int*   crow = conf_t + (size_t)blockIdx.x * NP;

    __shared__ unsigned int hist[256];
    __shared__ unsigned int s_prefix;
    __shared__ long long    s_want;

    unsigned int prefix = 0;
    long long want = nn;                      // 1-indexed rank (largest)

    for (int pass = 0; pass < 4; ++pass) {
        int shift = 24 - 8 * pass;
        hist[threadIdx.x] = 0;
        __syncthreads();
        for (int i = threadIdx.x; i < NP; i += 256) {
            unsigned int k = __float_as_uint(neg_conf_loss(prow, crow, i));
            bool match = (pass == 0) || ((k >> (shift + 8)) == prefix);
            if (match) atomicAdd(&hist[(k >> shift) & 255u], 1u);
        }
        __syncthreads();
        if (threadIdx.x == 0) {
            unsigned long long cum = 0;
            int d = 255;
            for (; d > 0; --d) {              // falls through to d=0
                unsigned long long h = hist[d];
                if (cum + h >= (unsigned long long)want) break;
                cum += h;
            }
            s_want   = want - (long long)cum;
            s_prefix = (prefix << 8) | (unsigned int)d;
        }
        __syncthreads();
        prefix = s_prefix;
        want   = s_want;
        __syncthreads();
    }

    // prefix == float bits of the nn-th largest value T.
    float T = __uint_as_float(prefix);
    double sgt = 0.0;
    long long cgt = 0;
    for (int i = threadIdx.x; i < NP; i += 256) {
        float lc = neg_conf_loss(prow, crow, i);
        if (__float_as_uint(lc) > prefix) { sgt += (double)lc; ++cgt; }
    }
#pragma unroll
    for (int off = 32; off > 0; off >>= 1) {
        sgt += __shfl_down(sgt, off, 64);
        cgt += __shfl_down(cgt, off, 64);
    }
    __shared__ double    rL[4];
    __shared__ long long rC[4];
    int lane = threadIdx.x & 63, wid = threadIdx.x >> 6;
    if (lane == 0) { rL[wid] = sgt; rC[wid] = cgt; }
    __syncthreads();
    if (threadIdx.x == 0) {
        double stot = rL[0] + rL[1] + rL[2] + rL[3];
        long long ctot = rC[0] + rC[1] + rC[2] + rC[3];
        double rowsum = stot + (double)(nn - ctot) * (double)T;
        atomicAdd(&ws[ACC_LOSS], rowsum);   // <=64 uncontended atomics
    }
}

__global__ void ssd_final(const double* __restrict__ ws,
                          float* __restrict__ out)
{
    out[0] = (float)(ws[ACC_LOSS] / ws[ACC_NPOS]);
}

extern "C" void kernel_launch(void* const* d_in, const int* in_sizes, int n_in,
                              void* d_out, int out_size, void* d_ws, size_t ws_size,
                              hipStream_t stream)
{
    const float* p      = (const float*)d_in[0];
    const float* loc_t  = (const float*)d_in[1];
    const int*   conf_t = (const int*)d_in[2];
    float*  out = (float*)d_out;
    double* ws  = (double*)d_ws;

    ssd_main<<<MAIN_BLOCKS, 256, 0, stream>>>(p, loc_t, conf_t, ws);
    ssd_reduce<<<1, 256, 0, stream>>>(ws);
    ssd_mine<<<NB, 256, 0, stream>>>(p, conf_t, ws);
    ssd_final<<<1, 1, 0, stream>>>(ws, out);
}